// Round 1
// baseline (319.475 us; speedup 1.0000x reference)
//
#include <hip/hip_runtime.h>
#include <stdint.h>

typedef __bf16 bf16;
typedef __bf16 bf16x8 __attribute__((ext_vector_type(8)));
typedef float f32x4 __attribute__((ext_vector_type(4)));

// XOR swizzle for [rows][32] bf16 LDS tiles (64B row stride): spreads the
// 16-lane column-slice reads across 8 banks. Apply on BOTH write and read.
__device__ __forceinline__ int swz(int row, int colb) {
    return (row * 64 + colb) ^ ((row & 7) << 4);
}

// ---------------- weight transpose + f32->bf16 ----------------
// W [1024][1024] row-major (K x N) -> WT bf16 [N][K]
__global__ __launch_bounds__(256) void wt_cvt(
    const float* __restrict__ w0, const float* __restrict__ w1,
    const float* __restrict__ w2, const float* __restrict__ w3,
    bf16* __restrict__ o0, bf16* __restrict__ o1,
    bf16* __restrict__ o2, bf16* __restrict__ o3)
{
    int z = blockIdx.z;
    const float* W = z == 0 ? w0 : z == 1 ? w1 : z == 2 ? w2 : w3;
    bf16* O = z == 0 ? o0 : z == 1 ? o1 : z == 2 ? o2 : o3;
    __shared__ float tile[32][33];
    int c0 = blockIdx.x * 32, r0 = blockIdx.y * 32;
    int tx = threadIdx.x, ty = threadIdx.y; // (32,8)
#pragma unroll
    for (int i = 0; i < 4; ++i)
        tile[ty + i * 8][tx] = W[(size_t)(r0 + ty + i * 8) * 1024 + c0 + tx];
    __syncthreads();
#pragma unroll
    for (int i = 0; i < 4; ++i)
        O[(size_t)(c0 + ty + i * 8) * 1024 + r0 + tx] = (bf16)tile[tx][ty + i * 8];
}

// ---------------- projection GEMM: X(f32 4096x1024) @ W -> head-major bf16 ----
// out layout: [(b*16+h)*1024 + s]*64 + d
__global__ __launch_bounds__(256) void proj_gemm(
    const float* __restrict__ Aq, const float* __restrict__ Ak, const float* __restrict__ Av,
    const bf16* __restrict__ Wq, const bf16* __restrict__ Wk, const bf16* __restrict__ Wv,
    bf16* __restrict__ Oq, bf16* __restrict__ Ok, bf16* __restrict__ Ov)
{
    int z = blockIdx.z;
    const float* A = z == 0 ? Aq : z == 1 ? Ak : Av;
    const bf16* WT = z == 0 ? Wq : z == 1 ? Wk : Wv;
    bf16* O = z == 0 ? Oq : z == 1 ? Ok : Ov;

    __shared__ bf16 Al[128 * 32];
    __shared__ bf16 Bl[128 * 32];

    int tid = threadIdx.x;
    int w = tid >> 6, l = tid & 63;
    int l15 = l & 15, lg = l >> 4;
    int m0 = blockIdx.y * 128, n0 = blockIdx.x * 128;
    int wm = (w >> 1) * 64, wn = (w & 1) * 64;

    const f32x4 fz = {0.f, 0.f, 0.f, 0.f};
    f32x4 acc[4][4];
#pragma unroll
    for (int i = 0; i < 4; ++i)
#pragma unroll
        for (int j = 0; j < 4; ++j) acc[i][j] = fz;

    int ar = tid >> 1, ac = (tid & 1) * 16;

    for (int k0 = 0; k0 < 1024; k0 += 32) {
        // A stage: f32 -> bf16
        const float* asrc = A + (size_t)(m0 + ar) * 1024 + k0 + ac;
        f32x4 f0 = *(const f32x4*)(asrc);
        f32x4 f1 = *(const f32x4*)(asrc + 4);
        f32x4 f2 = *(const f32x4*)(asrc + 8);
        f32x4 f3 = *(const f32x4*)(asrc + 12);
        bf16x8 b0, b1;
#pragma unroll
        for (int j = 0; j < 4; ++j) {
            b0[j] = (bf16)f0[j]; b0[4 + j] = (bf16)f1[j];
            b1[j] = (bf16)f2[j]; b1[4 + j] = (bf16)f3[j];
        }
        // B stage: WT rows n0..n0+127
        const bf16* bsrc = WT + (size_t)(n0 + ar) * 1024 + k0 + ac;
        bf16x8 bw0 = *(const bf16x8*)(bsrc);
        bf16x8 bw1 = *(const bf16x8*)(bsrc + 8);
        *(bf16x8*)((char*)Al + swz(ar, ac * 2))      = b0;
        *(bf16x8*)((char*)Al + swz(ar, ac * 2 + 16)) = b1;
        *(bf16x8*)((char*)Bl + swz(ar, ac * 2))      = bw0;
        *(bf16x8*)((char*)Bl + swz(ar, ac * 2 + 16)) = bw1;
        __syncthreads();
        bf16x8 af[4], bv[4];
#pragma unroll
        for (int i = 0; i < 4; ++i)
            af[i] = *(const bf16x8*)((const char*)Al + swz(wm + i * 16 + l15, lg * 16));
#pragma unroll
        for (int j = 0; j < 4; ++j)
            bv[j] = *(const bf16x8*)((const char*)Bl + swz(wn + j * 16 + l15, lg * 16));
#pragma unroll
        for (int i = 0; i < 4; ++i)
#pragma unroll
            for (int j = 0; j < 4; ++j)
                acc[i][j] = __builtin_amdgcn_mfma_f32_16x16x32_bf16(af[i], bv[j], acc[i][j], 0, 0, 0);
        __syncthreads();
    }
#pragma unroll
    for (int i = 0; i < 4; ++i)
#pragma unroll
        for (int j = 0; j < 4; ++j)
#pragma unroll
            for (int r = 0; r < 4; ++r) {
                int m = m0 + wm + i * 16 + lg * 4 + r;
                int n = n0 + wn + j * 16 + l15;
                int bb = m >> 10, s = m & 1023, h = n >> 6, d = n & 63;
                O[((size_t)(bb * 16 + h) * 1024 + s) * 64 + d] = (bf16)acc[i][j][r];
            }
}

// ---------------- Vh (B,H,S,64) -> VhT (B,H,64,S) ----------------
__global__ __launch_bounds__(512) void vh_t(const bf16* __restrict__ Vh, bf16* __restrict__ VhT)
{
    __shared__ bf16 tile[64][65];
    int bh = blockIdx.y;
    int s0 = blockIdx.x * 64;
    int tx = threadIdx.x, ty = threadIdx.y; // (64,8)
    const bf16* src = Vh + (size_t)bh * 1024 * 64;
#pragma unroll
    for (int i = 0; i < 8; ++i)
        tile[ty + i * 8][tx] = src[(size_t)(s0 + ty + i * 8) * 64 + tx];
    __syncthreads();
    bf16* dst = VhT + (size_t)bh * 64 * 1024;
#pragma unroll
    for (int i = 0; i < 8; ++i)
        dst[(size_t)(ty + i * 8) * 1024 + s0 + tx] = tile[tx][ty + i * 8];
}

// ---------------- QK^T + mask + softmax -> attn f32 ----------------
// grid (64 qtiles, 64 bh), block 512 (8 waves). Each wave: 16 rows x 128 keys.
__global__ __launch_bounds__(512) void attn_kernel(
    const bf16* __restrict__ Qh, const bf16* __restrict__ Kh,
    const int* __restrict__ mask, float* __restrict__ attn_out)
{
    int bh = blockIdx.y;
    int b = bh >> 4;
    int q0 = blockIdx.x * 16;
    int tid = threadIdx.x;
    int w = tid >> 6, l = tid & 63;
    int l15 = l & 15, lg = l >> 4;
    int wn0 = w * 128;
    const bf16* Qb = Qh + (size_t)bh * 1024 * 64;
    const bf16* Kb = Kh + (size_t)bh * 1024 * 64;

    const f32x4 fz = {0.f, 0.f, 0.f, 0.f};
    f32x4 acc[8];
#pragma unroll
    for (int f = 0; f < 8; ++f) acc[f] = fz;

#pragma unroll
    for (int kk = 0; kk < 2; ++kk) {
        bf16x8 a = *(const bf16x8*)(Qb + (size_t)(q0 + l15) * 64 + kk * 32 + lg * 8);
#pragma unroll
        for (int f = 0; f < 8; ++f) {
            bf16x8 kv = *(const bf16x8*)(Kb + (size_t)(wn0 + f * 16 + l15) * 64 + kk * 32 + lg * 8);
            acc[f] = __builtin_amdgcn_mfma_f32_16x16x32_bf16(a, kv, acc[f], 0, 0, 0);
        }
    }
    // scale + mask
    const int* mrow = mask + (size_t)b * 1024 * 1024 + (size_t)q0 * 1024;
    float s[8][4];
#pragma unroll
    for (int f = 0; f < 8; ++f)
#pragma unroll
        for (int r = 0; r < 4; ++r) {
            int qr = lg * 4 + r;
            int key = wn0 + f * 16 + l15;
            s[f][r] = mrow[qr * 1024 + key] ? acc[f][r] * 0.125f : -1e9f;
        }
    __shared__ float red[16][8];
    // row max: per-lane over frags, then 16-lane group, then cross-wave
    float pm[4];
#pragma unroll
    for (int r = 0; r < 4; ++r) {
        float m = s[0][r];
#pragma unroll
        for (int f = 1; f < 8; ++f) m = fmaxf(m, s[f][r]);
        pm[r] = m;
    }
#pragma unroll
    for (int msk = 8; msk >= 1; msk >>= 1)
#pragma unroll
        for (int r = 0; r < 4; ++r) pm[r] = fmaxf(pm[r], __shfl_xor(pm[r], msk, 64));
    if (l15 == 0) {
#pragma unroll
        for (int r = 0; r < 4; ++r) red[lg * 4 + r][w] = pm[r];
    }
    __syncthreads();
    float rowm[4];
#pragma unroll
    for (int r = 0; r < 4; ++r) {
        float m = red[lg * 4 + r][0];
#pragma unroll
        for (int ww = 1; ww < 8; ++ww) m = fmaxf(m, red[lg * 4 + r][ww]);
        rowm[r] = m;
    }
    __syncthreads();
    // exp + row sum
    float p[8][4];
    float ps[4] = {0.f, 0.f, 0.f, 0.f};
#pragma unroll
    for (int f = 0; f < 8; ++f)
#pragma unroll
        for (int r = 0; r < 4; ++r) {
            p[f][r] = __expf(s[f][r] - rowm[r]);
            ps[r] += p[f][r];
        }
#pragma unroll
    for (int msk = 8; msk >= 1; msk >>= 1)
#pragma unroll
        for (int r = 0; r < 4; ++r) ps[r] += __shfl_xor(ps[r], msk, 64);
    if (l15 == 0) {
#pragma unroll
        for (int r = 0; r < 4; ++r) red[lg * 4 + r][w] = ps[r];
    }
    __syncthreads();
    float inv[4];
#pragma unroll
    for (int r = 0; r < 4; ++r) {
        float t = red[lg * 4 + r][0];
#pragma unroll
        for (int ww = 1; ww < 8; ++ww) t += red[lg * 4 + r][ww];
        inv[r] = 1.f / t;
    }
    float* aout = attn_out + ((size_t)bh * 1024 + q0) * 1024;
#pragma unroll
    for (int f = 0; f < 8; ++f)
#pragma unroll
        for (int r = 0; r < 4; ++r)
            aout[(size_t)(lg * 4 + r) * 1024 + wn0 + f * 16 + l15] = p[f][r] * inv[r];
}

// ---------------- PV GEMM: attn(f32 SxS) @ Vh -> ctx bf16 (B,S,1024) --------
__global__ __launch_bounds__(256) void pv_gemm(
    const float* __restrict__ attnp, const bf16* __restrict__ VhT, bf16* __restrict__ ctx)
{
    int bh = blockIdx.y;
    int b = bh >> 4, h = bh & 15;
    int m0 = blockIdx.x * 128;
    __shared__ bf16 Al[128 * 32];
    __shared__ bf16 Bl[64 * 32];
    int tid = threadIdx.x;
    int w = tid >> 6, l = tid & 63;
    int l15 = l & 15, lg = l >> 4;
    int wm = (w >> 1) * 64, wn = (w & 1) * 32;
    const float* Abase = attnp + (size_t)bh * 1024 * 1024;
    const bf16* Bbase = VhT + (size_t)bh * 64 * 1024;

    const f32x4 fz = {0.f, 0.f, 0.f, 0.f};
    f32x4 acc[4][2];
#pragma unroll
    for (int i = 0; i < 4; ++i) { acc[i][0] = fz; acc[i][1] = fz; }

    int ar = tid >> 1, ac = (tid & 1) * 16;
    int br = tid >> 2, bc = (tid & 3) * 8;

    for (int k0 = 0; k0 < 1024; k0 += 32) {
        const float* asrc = Abase + (size_t)(m0 + ar) * 1024 + k0 + ac;
        f32x4 f0 = *(const f32x4*)(asrc);
        f32x4 f1 = *(const f32x4*)(asrc + 4);
        f32x4 f2 = *(const f32x4*)(asrc + 8);
        f32x4 f3 = *(const f32x4*)(asrc + 12);
        bf16x8 b0, b1;
#pragma unroll
        for (int j = 0; j < 4; ++j) {
            b0[j] = (bf16)f0[j]; b0[4 + j] = (bf16)f1[j];
            b1[j] = (bf16)f2[j]; b1[4 + j] = (bf16)f3[j];
        }
        bf16x8 bw = *(const bf16x8*)(Bbase + (size_t)br * 1024 + k0 + bc);
        *(bf16x8*)((char*)Al + swz(ar, ac * 2))      = b0;
        *(bf16x8*)((char*)Al + swz(ar, ac * 2 + 16)) = b1;
        *(bf16x8*)((char*)Bl + swz(br, bc * 2))      = bw;
        __syncthreads();
        bf16x8 af[4], bv[2];
#pragma unroll
        for (int i = 0; i < 4; ++i)
            af[i] = *(const bf16x8*)((const char*)Al + swz(wm + i * 16 + l15, lg * 16));
#pragma unroll
        for (int j = 0; j < 2; ++j)
            bv[j] = *(const bf16x8*)((const char*)Bl + swz(wn + j * 16 + l15, lg * 16));
#pragma unroll
        for (int i = 0; i < 4; ++i)
#pragma unroll
            for (int j = 0; j < 2; ++j)
                acc[i][j] = __builtin_amdgcn_mfma_f32_16x16x32_bf16(af[i], bv[j], acc[i][j], 0, 0, 0);
        __syncthreads();
    }
#pragma unroll
    for (int i = 0; i < 4; ++i)
#pragma unroll
        for (int j = 0; j < 2; ++j)
#pragma unroll
            for (int r = 0; r < 4; ++r) {
                int srow = m0 + wm + i * 16 + lg * 4 + r;
                int dv = wn + j * 16 + l15;
                ctx[((size_t)(b * 1024 + srow)) * 1024 + h * 64 + dv] = (bf16)acc[i][j][r];
            }
}

// ---------------- FC GEMM + residual -> preLN f32 ----------------
__global__ __launch_bounds__(256) void fc_gemm(
    const bf16* __restrict__ ctx, const bf16* __restrict__ WT,
    const float* __restrict__ resid, float* __restrict__ preLN)
{
    __shared__ bf16 Al[128 * 32];
    __shared__ bf16 Bl[128 * 32];
    int tid = threadIdx.x;
    int w = tid >> 6, l = tid & 63;
    int l15 = l & 15, lg = l >> 4;
    int m0 = blockIdx.y * 128, n0 = blockIdx.x * 128;
    int wm = (w >> 1) * 64, wn = (w & 1) * 64;

    const f32x4 fz = {0.f, 0.f, 0.f, 0.f};
    f32x4 acc[4][4];
#pragma unroll
    for (int i = 0; i < 4; ++i)
#pragma unroll
        for (int j = 0; j < 4; ++j) acc[i][j] = fz;

    int ar = tid >> 1, ac = (tid & 1) * 16;

    for (int k0 = 0; k0 < 1024; k0 += 32) {
        const bf16* asrc = ctx + (size_t)(m0 + ar) * 1024 + k0 + ac;
        bf16x8 a0 = *(const bf16x8*)(asrc);
        bf16x8 a1 = *(const bf16x8*)(asrc + 8);
        const bf16* bsrc = WT + (size_t)(n0 + ar) * 1024 + k0 + ac;
        bf16x8 bw0 = *(const bf16x8*)(bsrc);
        bf16x8 bw1 = *(const bf16x8*)(bsrc + 8);
        *(bf16x8*)((char*)Al + swz(ar, ac * 2))      = a0;
        *(bf16x8*)((char*)Al + swz(ar, ac * 2 + 16)) = a1;
        *(bf16x8*)((char*)Bl + swz(ar, ac * 2))      = bw0;
        *(bf16x8*)((char*)Bl + swz(ar, ac * 2 + 16)) = bw1;
        __syncthreads();
        bf16x8 af[4], bv[4];
#pragma unroll
        for (int i = 0; i < 4; ++i)
            af[i] = *(const bf16x8*)((const char*)Al + swz(wm + i * 16 + l15, lg * 16));
#pragma unroll
        for (int j = 0; j < 4; ++j)
            bv[j] = *(const bf16x8*)((const char*)Bl + swz(wn + j * 16 + l15, lg * 16));
#pragma unroll
        for (int i = 0; i < 4; ++i)
#pragma unroll
            for (int j = 0; j < 4; ++j)
                acc[i][j] = __builtin_amdgcn_mfma_f32_16x16x32_bf16(af[i], bv[j], acc[i][j], 0, 0, 0);
        __syncthreads();
    }
#pragma unroll
    for (int i = 0; i < 4; ++i)
#pragma unroll
        for (int j = 0; j < 4; ++j)
#pragma unroll
            for (int r = 0; r < 4; ++r) {
                int m = m0 + wm + i * 16 + lg * 4 + r;
                int n = n0 + wn + j * 16 + l15;
                preLN[(size_t)m * 1024 + n] = acc[i][j][r] + resid[(size_t)m * 1024 + n];
            }
}

// ---------------- LayerNorm ----------------
__global__ __launch_bounds__(256) void ln_kernel(
    const float* __restrict__ x, const float* __restrict__ gamma,
    const float* __restrict__ beta, float* __restrict__ out)
{
    int row = blockIdx.x, t = threadIdx.x;
    const float* xr = x + (size_t)row * 1024;
    f32x4 v = *(const f32x4*)(xr + t * 4);
    float s = v[0] + v[1] + v[2] + v[3];
    float s2 = v[0] * v[0] + v[1] * v[1] + v[2] * v[2] + v[3] * v[3];
#pragma unroll
    for (int m = 1; m < 64; m <<= 1) {
        s += __shfl_xor(s, m, 64);
        s2 += __shfl_xor(s2, m, 64);
    }
    __shared__ float rs[4], rs2[4];
    if ((t & 63) == 0) { rs[t >> 6] = s; rs2[t >> 6] = s2; }
    __syncthreads();
    float S = rs[0] + rs[1] + rs[2] + rs[3];
    float S2 = rs2[0] + rs2[1] + rs2[2] + rs2[3];
    float mu = S * (1.f / 1024.f);
    float var = S2 * (1.f / 1024.f) - mu * mu;
    float rinv = rsqrtf(var + 1e-6f);
    f32x4 g = *(const f32x4*)(gamma + t * 4);
    f32x4 bb = *(const f32x4*)(beta + t * 4);
    f32x4 o;
#pragma unroll
    for (int j = 0; j < 4; ++j) o[j] = (v[j] - mu) * rinv * g[j] + bb[j];
    *(f32x4*)(out + (size_t)row * 1024 + t * 4) = o;
}

extern "C" void kernel_launch(void* const* d_in, const int* in_sizes, int n_in,
                              void* d_out, int out_size, void* d_ws, size_t ws_size,
                              hipStream_t stream) {
    const float* q     = (const float*)d_in[0];
    const float* k     = (const float*)d_in[1];
    const float* v     = (const float*)d_in[2];
    const int*   mask  = (const int*)d_in[3];
    const float* w_qs  = (const float*)d_in[4];
    const float* w_ks  = (const float*)d_in[5];
    const float* w_vs  = (const float*)d_in[6];
    const float* w_fc  = (const float*)d_in[7];
    const float* gamma = (const float*)d_in[8];
    const float* beta  = (const float*)d_in[9];

    float* out  = (float*)d_out;
    float* attn = out + (size_t)4 * 1024 * 1024; // second tuple output

    char* ws = (char*)d_ws;
    bf16* wqT   = (bf16*)(ws + (0ull  << 20));
    bf16* wkT   = (bf16*)(ws + (2ull  << 20));
    bf16* wvT   = (bf16*)(ws + (4ull  << 20));
    bf16* wfcT  = (bf16*)(ws + (6ull  << 20));
    bf16* Qh    = (bf16*)(ws + (8ull  << 20));
    bf16* Kh    = (bf16*)(ws + (16ull << 20));
    bf16* Vh    = (bf16*)(ws + (24ull << 20));
    bf16* VhT   = (bf16*)(ws + (32ull << 20));
    bf16* ctx   = (bf16*)(ws + (40ull << 20));
    float* preLN = (float*)(ws + (48ull << 20));

    wt_cvt<<<dim3(32, 32, 4), dim3(32, 8), 0, stream>>>(w_qs, w_ks, w_vs, w_fc,
                                                        wqT, wkT, wvT, wfcT);
    proj_gemm<<<dim3(8, 32, 3), 256, 0, stream>>>(q, k, v, wqT, wkT, wvT, Qh, Kh, Vh);
    vh_t<<<dim3(16, 64), dim3(64, 8), 0, stream>>>(Vh, VhT);
    attn_kernel<<<dim3(64, 64), 512, 0, stream>>>(Qh, Kh, mask, attn);
    pv_gemm<<<dim3(8, 64), 256, 0, stream>>>(attn, VhT, ctx);
    fc_gemm<<<dim3(8, 32), 256, 0, stream>>>(ctx, wfcT, q, preLN);
    ln_kernel<<<4096, 256, 0, stream>>>(preLN, gamma, beta, out);
}

// Round 2
// 301.641 us; speedup vs baseline: 1.0591x; 1.0591x over previous
//
#include <hip/hip_runtime.h>
#include <stdint.h>

typedef __bf16 bf16;
typedef __bf16 bf16x2 __attribute__((ext_vector_type(2)));
typedef __bf16 bf16x8 __attribute__((ext_vector_type(8)));
typedef float f32x4 __attribute__((ext_vector_type(4)));
typedef float f32x2 __attribute__((ext_vector_type(2)));
typedef int i32x4 __attribute__((ext_vector_type(4)));
typedef unsigned u32x4 __attribute__((ext_vector_type(4)));

// XOR swizzle for [rows][32] bf16 LDS tiles (64B row stride).
__device__ __forceinline__ int swz(int row, int colb) {
    return (row * 64 + colb) ^ ((row & 7) << 4);
}

__device__ __forceinline__ unsigned packb(float a, float b) {
    bf16x2 t; t[0] = (bf16)a; t[1] = (bf16)b;
    return __builtin_bit_cast(unsigned, t);
}

// ---------------- weight transpose + f32->bf16 ----------------
__global__ __launch_bounds__(256) void wt_cvt(
    const float* __restrict__ w0, const float* __restrict__ w1,
    const float* __restrict__ w2, const float* __restrict__ w3,
    bf16* __restrict__ o0, bf16* __restrict__ o1,
    bf16* __restrict__ o2, bf16* __restrict__ o3)
{
    int z = blockIdx.z;
    const float* W = z == 0 ? w0 : z == 1 ? w1 : z == 2 ? w2 : w3;
    bf16* O = z == 0 ? o0 : z == 1 ? o1 : z == 2 ? o2 : o3;
    __shared__ float tile[32][33];
    int c0 = blockIdx.x * 32, r0 = blockIdx.y * 32;
    int tx = threadIdx.x, ty = threadIdx.y; // (32,8)
#pragma unroll
    for (int i = 0; i < 4; ++i)
        tile[ty + i * 8][tx] = W[(size_t)(r0 + ty + i * 8) * 1024 + c0 + tx];
    __syncthreads();
#pragma unroll
    for (int i = 0; i < 4; ++i)
        O[(size_t)(c0 + ty + i * 8) * 1024 + r0 + tx] = (bf16)tile[tx][ty + i * 8];
}

// ---------------- projection GEMM -> head-major bf16 ----------------
__global__ __launch_bounds__(256) void proj_gemm(
    const float* __restrict__ Aq, const float* __restrict__ Ak, const float* __restrict__ Av,
    const bf16* __restrict__ Wq, const bf16* __restrict__ Wk, const bf16* __restrict__ Wv,
    bf16* __restrict__ Oq, bf16* __restrict__ Ok, bf16* __restrict__ Ov)
{
    int z = blockIdx.z;
    const float* A = z == 0 ? Aq : z == 1 ? Ak : Av;
    const bf16* WT = z == 0 ? Wq : z == 1 ? Wk : Wv;
    bf16* O = z == 0 ? Oq : z == 1 ? Ok : Ov;

    __shared__ bf16 Al[128 * 32];
    __shared__ bf16 Bl[128 * 32];

    int tid = threadIdx.x;
    int w = tid >> 6, l = tid & 63;
    int l15 = l & 15, lg = l >> 4;
    int m0 = blockIdx.y * 128, n0 = blockIdx.x * 128;
    int wm = (w >> 1) * 64, wn = (w & 1) * 64;

    const f32x4 fz = {0.f, 0.f, 0.f, 0.f};
    f32x4 acc[4][4];
#pragma unroll
    for (int i = 0; i < 4; ++i)
#pragma unroll
        for (int j = 0; j < 4; ++j) acc[i][j] = fz;

    int ar = tid >> 1, ac = (tid & 1) * 16;

    for (int k0 = 0; k0 < 1024; k0 += 32) {
        const float* asrc = A + (size_t)(m0 + ar) * 1024 + k0 + ac;
        f32x4 f0 = *(const f32x4*)(asrc);
        f32x4 f1 = *(const f32x4*)(asrc + 4);
        f32x4 f2 = *(const f32x4*)(asrc + 8);
        f32x4 f3 = *(const f32x4*)(asrc + 12);
        bf16x8 b0, b1;
#pragma unroll
        for (int j = 0; j < 4; ++j) {
            b0[j] = (bf16)f0[j]; b0[4 + j] = (bf16)f1[j];
            b1[j] = (bf16)f2[j]; b1[4 + j] = (bf16)f3[j];
        }
        const bf16* bsrc = WT + (size_t)(n0 + ar) * 1024 + k0 + ac;
        bf16x8 bw0 = *(const bf16x8*)(bsrc);
        bf16x8 bw1 = *(const bf16x8*)(bsrc + 8);
        *(bf16x8*)((char*)Al + swz(ar, ac * 2))      = b0;
        *(bf16x8*)((char*)Al + swz(ar, ac * 2 + 16)) = b1;
        *(bf16x8*)((char*)Bl + swz(ar, ac * 2))      = bw0;
        *(bf16x8*)((char*)Bl + swz(ar, ac * 2 + 16)) = bw1;
        __syncthreads();
        bf16x8 af[4], bv[4];
#pragma unroll
        for (int i = 0; i < 4; ++i)
            af[i] = *(const bf16x8*)((const char*)Al + swz(wm + i * 16 + l15, lg * 16));
#pragma unroll
        for (int j = 0; j < 4; ++j)
            bv[j] = *(const bf16x8*)((const char*)Bl + swz(wn + j * 16 + l15, lg * 16));
#pragma unroll
        for (int i = 0; i < 4; ++i)
#pragma unroll
            for (int j = 0; j < 4; ++j)
                acc[i][j] = __builtin_amdgcn_mfma_f32_16x16x32_bf16(af[i], bv[j], acc[i][j], 0, 0, 0);
        __syncthreads();
    }
#pragma unroll
    for (int i = 0; i < 4; ++i)
#pragma unroll
        for (int j = 0; j < 4; ++j)
#pragma unroll
            for (int r = 0; r < 4; ++r) {
                int m = m0 + wm + i * 16 + lg * 4 + r;
                int n = n0 + wn + j * 16 + l15;
                int bb = m >> 10, s = m & 1023, h = n >> 6, d = n & 63;
                O[((size_t)(bb * 16 + h) * 1024 + s) * 64 + d] = (bf16)acc[i][j][r];
            }
}

// ---------------- Vh (B,H,S,64) -> VhT (B,H,64,S) ----------------
__global__ __launch_bounds__(512) void vh_t(const bf16* __restrict__ Vh, bf16* __restrict__ VhT)
{
    __shared__ bf16 tile[64][65];
    int bh = blockIdx.y;
    int s0 = blockIdx.x * 64;
    int tx = threadIdx.x, ty = threadIdx.y; // (64,8)
    const bf16* src = Vh + (size_t)bh * 1024 * 64;
#pragma unroll
    for (int i = 0; i < 8; ++i)
        tile[ty + i * 8][tx] = src[(size_t)(s0 + ty + i * 8) * 64 + tx];
    __syncthreads();
    bf16* dst = VhT + (size_t)bh * 64 * 1024;
#pragma unroll
    for (int i = 0; i < 8; ++i)
        dst[(size_t)(ty + i * 8) * 1024 + s0 + tx] = tile[tx][ty + i * 8];
}

// ---------------- fused QK^T + mask + softmax + attn-write + PV ----------------
// grid (64 qtiles, 64 bh), block 512 (8 waves). Wave w owns keys [w*128,w*128+128).
// Swapped QK^T: st[f] = mfma(A=K, B=Q) -> S^T[key][q]; lane(l15,lg) reg r holds
// S^T[wn0+f*16+lg*4+r][q0+l15].
__global__ __launch_bounds__(512) void attn_pv(
    const bf16* __restrict__ Qh, const bf16* __restrict__ Kh,
    const bf16* __restrict__ VhT, const int* __restrict__ mask,
    float* __restrict__ attn_out, bf16* __restrict__ ctx)
{
    int bh = blockIdx.y;
    int b = bh >> 4, h = bh & 15;
    int q0 = blockIdx.x * 16;
    int tid = threadIdx.x;
    int w = tid >> 6, l = tid & 63;
    int l15 = l & 15, lg = l >> 4;
    int wn0 = w * 128;
    const bf16* Qb = Qh + (size_t)bh * 1024 * 64;
    const bf16* Kb = Kh + (size_t)bh * 1024 * 64;
    const bf16* Vt = VhT + (size_t)bh * 64 * 1024;

    const f32x4 fz = {0.f, 0.f, 0.f, 0.f};
    f32x4 st[8];
#pragma unroll
    for (int f = 0; f < 8; ++f) st[f] = fz;

#pragma unroll
    for (int kk = 0; kk < 2; ++kk) {
        bf16x8 qf = *(const bf16x8*)(Qb + (size_t)(q0 + l15) * 64 + kk * 32 + lg * 8);
#pragma unroll
        for (int f = 0; f < 8; ++f) {
            bf16x8 kf = *(const bf16x8*)(Kb + (size_t)(wn0 + f * 16 + l15) * 64 + kk * 32 + lg * 8);
            st[f] = __builtin_amdgcn_mfma_f32_16x16x32_bf16(kf, qf, st[f], 0, 0, 0);
        }
    }
    // mask + scale; q = q0+l15, key = wn0 + f*16 + lg*4 + r
    const int* mrow = mask + (size_t)b * 1024 * 1024 + (size_t)(q0 + l15) * 1024 + wn0;
    float s[8][4];
#pragma unroll
    for (int f = 0; f < 8; ++f) {
        i32x4 mm = *(const i32x4*)(mrow + f * 16 + lg * 4);
#pragma unroll
        for (int r = 0; r < 4; ++r)
            s[f][r] = mm[r] ? st[f][r] * 0.125f : -1e9f;
    }
    __shared__ float redm[16][8];
    __shared__ float reds[16][8];
    // row max over this wave's 128 keys (q fixed per lane = l15)
    float pm = s[0][0];
#pragma unroll
    for (int f = 0; f < 8; ++f)
#pragma unroll
        for (int r = 0; r < 4; ++r) pm = fmaxf(pm, s[f][r]);
    pm = fmaxf(pm, __shfl_xor(pm, 16, 64));
    pm = fmaxf(pm, __shfl_xor(pm, 32, 64));
    if (l < 16) redm[l15][w] = pm;
    __syncthreads();
    float rowm = redm[l15][0];
#pragma unroll
    for (int ww = 1; ww < 8; ++ww) rowm = fmaxf(rowm, redm[l15][ww]);
    // exp + row sum
    float p[8][4];
    float ps = 0.f;
#pragma unroll
    for (int f = 0; f < 8; ++f)
#pragma unroll
        for (int r = 0; r < 4; ++r) {
            p[f][r] = __expf(s[f][r] - rowm);
            ps += p[f][r];
        }
    ps += __shfl_xor(ps, 16, 64);
    ps += __shfl_xor(ps, 32, 64);
    if (l < 16) reds[l15][w] = ps;
    __syncthreads();
    float tsum = reds[l15][0];
#pragma unroll
    for (int ww = 1; ww < 8; ++ww) tsum += reds[l15][ww];
    float inv = 1.f / tsum;

    // normalize, write attn (f32x4 per f), pack to bf16 pairs for PV
    float* aout = attn_out + ((size_t)bh * 1024 + q0 + l15) * 1024 + wn0;
    unsigned pk[8][2];
#pragma unroll
    for (int f = 0; f < 8; ++f) {
        f32x4 o;
#pragma unroll
        for (int r = 0; r < 4; ++r) o[r] = p[f][r] * inv;
        *(f32x4*)(aout + f * 16 + lg * 4) = o;
        pk[f][0] = packb(o[0], o[1]);
        pk[f][1] = packb(o[2], o[3]);
    }

    // PV: O^T = V^T @ p^T over this wave's 128 keys.
    // B-frag for k-step ks: lane(l15,lg) needs p^T[wn0+ks*32+lg*8+j][q0+l15].
    // sources: lane srcA = l15+32*(lg&1) (j=0..3), srcB = srcA+16 (j=4..7),
    // even fragment (f=2ks) for lg<2, odd (f=2ks+1) for lg>=2.
    f32x4 oacc[4];
#pragma unroll
    for (int d0 = 0; d0 < 4; ++d0) oacc[d0] = fz;
    int srcA = l15 + 32 * (lg & 1);
    int srcB = srcA + 16;
    bool fo = lg >= 2;
#pragma unroll
    for (int ks = 0; ks < 4; ++ks) {
        unsigned e0 = pk[2 * ks][0], e1 = pk[2 * ks][1];
        unsigned o0 = pk[2 * ks + 1][0], o1 = pk[2 * ks + 1][1];
        unsigned ae0 = (unsigned)__shfl((int)e0, srcA, 64);
        unsigned ae1 = (unsigned)__shfl((int)e1, srcA, 64);
        unsigned ao0 = (unsigned)__shfl((int)o0, srcA, 64);
        unsigned ao1 = (unsigned)__shfl((int)o1, srcA, 64);
        unsigned be0 = (unsigned)__shfl((int)e0, srcB, 64);
        unsigned be1 = (unsigned)__shfl((int)e1, srcB, 64);
        unsigned bo0 = (unsigned)__shfl((int)o0, srcB, 64);
        unsigned bo1 = (unsigned)__shfl((int)o1, srcB, 64);
        u32x4 fr;
        fr[0] = fo ? ao0 : ae0;
        fr[1] = fo ? ao1 : ae1;
        fr[2] = fo ? bo0 : be0;
        fr[3] = fo ? bo1 : be1;
        bf16x8 pf = __builtin_bit_cast(bf16x8, fr);
#pragma unroll
        for (int d0 = 0; d0 < 4; ++d0) {
            bf16x8 vf = *(const bf16x8*)(Vt + (size_t)(d0 * 16 + l15) * 1024 + wn0 + ks * 32 + lg * 8);
            oacc[d0] = __builtin_amdgcn_mfma_f32_16x16x32_bf16(vf, pf, oacc[d0], 0, 0, 0);
        }
    }
    // cross-wave reduction of O^T partials: part[w][q][d]
    __shared__ float part[8][16][68];
#pragma unroll
    for (int d0 = 0; d0 < 4; ++d0)
#pragma unroll
        for (int r = 0; r < 4; ++r)
            part[w][l15][d0 * 16 + lg * 4 + r] = oacc[d0][r];
    __syncthreads();
    int q = (tid * 2) >> 6, d = (tid * 2) & 63;
    float s0 = 0.f, s1 = 0.f;
#pragma unroll
    for (int ww = 0; ww < 8; ++ww) {
        f32x2 t = *(const f32x2*)&part[ww][q][d];
        s0 += t[0]; s1 += t[1];
    }
    bf16x2 cv; cv[0] = (bf16)s0; cv[1] = (bf16)s1;
    *(bf16x2*)(ctx + ((size_t)(b * 1024 + q0 + q)) * 1024 + h * 64 + d) = cv;
}

// ---------------- FC GEMM + residual -> preLN f32 ----------------
__global__ __launch_bounds__(256) void fc_gemm(
    const bf16* __restrict__ ctx, const bf16* __restrict__ WT,
    const float* __restrict__ resid, float* __restrict__ preLN)
{
    __shared__ bf16 Al[128 * 32];
    __shared__ bf16 Bl[128 * 32];
    int tid = threadIdx.x;
    int w = tid >> 6, l = tid & 63;
    int l15 = l & 15, lg = l >> 4;
    int m0 = blockIdx.y * 128, n0 = blockIdx.x * 128;
    int wm = (w >> 1) * 64, wn = (w & 1) * 64;

    const f32x4 fz = {0.f, 0.f, 0.f, 0.f};
    f32x4 acc[4][4];
#pragma unroll
    for (int i = 0; i < 4; ++i)
#pragma unroll
        for (int j = 0; j < 4; ++j) acc[i][j] = fz;

    int ar = tid >> 1, ac = (tid & 1) * 16;

    for (int k0 = 0; k0 < 1024; k0 += 32) {
        const bf16* asrc = ctx + (size_t)(m0 + ar) * 1024 + k0 + ac;
        bf16x8 a0 = *(const bf16x8*)(asrc);
        bf16x8 a1 = *(const bf16x8*)(asrc + 8);
        const bf16* bsrc = WT + (size_t)(n0 + ar) * 1024 + k0 + ac;
        bf16x8 bw0 = *(const bf16x8*)(bsrc);
        bf16x8 bw1 = *(const bf16x8*)(bsrc + 8);
        *(bf16x8*)((char*)Al + swz(ar, ac * 2))      = a0;
        *(bf16x8*)((char*)Al + swz(ar, ac * 2 + 16)) = a1;
        *(bf16x8*)((char*)Bl + swz(ar, ac * 2))      = bw0;
        *(bf16x8*)((char*)Bl + swz(ar, ac * 2 + 16)) = bw1;
        __syncthreads();
        bf16x8 af[4], bv[4];
#pragma unroll
        for (int i = 0; i < 4; ++i)
            af[i] = *(const bf16x8*)((const char*)Al + swz(wm + i * 16 + l15, lg * 16));
#pragma unroll
        for (int j = 0; j < 4; ++j)
            bv[j] = *(const bf16x8*)((const char*)Bl + swz(wn + j * 16 + l15, lg * 16));
#pragma unroll
        for (int i = 0; i < 4; ++i)
#pragma unroll
            for (int j = 0; j < 4; ++j)
                acc[i][j] = __builtin_amdgcn_mfma_f32_16x16x32_bf16(af[i], bv[j], acc[i][j], 0, 0, 0);
        __syncthreads();
    }
#pragma unroll
    for (int i = 0; i < 4; ++i)
#pragma unroll
        for (int j = 0; j < 4; ++j)
#pragma unroll
            for (int r = 0; r < 4; ++r) {
                int m = m0 + wm + i * 16 + lg * 4 + r;
                int n = n0 + wn + j * 16 + l15;
                preLN[(size_t)m * 1024 + n] = acc[i][j][r] + resid[(size_t)m * 1024 + n];
            }
}

// ---------------- LayerNorm ----------------
__global__ __launch_bounds__(256) void ln_kernel(
    const float* __restrict__ x, const float* __restrict__ gamma,
    const float* __restrict__ beta, float* __restrict__ out)
{
    int row = blockIdx.x, t = threadIdx.x;
    const float* xr = x + (size_t)row * 1024;
    f32x4 v = *(const f32x4*)(xr + t * 4);
    float s = v[0] + v[1] + v[2] + v[3];
    float s2 = v[0] * v[0] + v[1] * v[1] + v[2] * v[2] + v[3] * v[3];
#pragma unroll
    for (int m = 1; m < 64; m <<= 1) {
        s += __shfl_xor(s, m, 64);
        s2 += __shfl_xor(s2, m, 64);
    }
    __shared__ float rs[4], rs2[4];
    if ((t & 63) == 0) { rs[t >> 6] = s; rs2[t >> 6] = s2; }
    __syncthreads();
    float S = rs[0] + rs[1] + rs[2] + rs[3];
    float S2 = rs2[0] + rs2[1] + rs2[2] + rs2[3];
    float mu = S * (1.f / 1024.f);
    float var = S2 * (1.f / 1024.f) - mu * mu;
    float rinv = rsqrtf(var + 1e-6f);
    f32x4 g = *(const f32x4*)(gamma + t * 4);
    f32x4 bb = *(const f32x4*)(beta + t * 4);
    f32x4 o;
#pragma unroll
    for (int j = 0; j < 4; ++j) o[j] = (v[j] - mu) * rinv * g[j] + bb[j];
    *(f32x4*)(out + (size_t)row * 1024 + t * 4) = o;
}

extern "C" void kernel_launch(void* const* d_in, const int* in_sizes, int n_in,
                              void* d_out, int out_size, void* d_ws, size_t ws_size,
                              hipStream_t stream) {
    const float* q     = (const float*)d_in[0];
    const float* k     = (const float*)d_in[1];
    const float* v     = (const float*)d_in[2];
    const int*   mask  = (const int*)d_in[3];
    const float* w_qs  = (const float*)d_in[4];
    const float* w_ks  = (const float*)d_in[5];
    const float* w_vs  = (const float*)d_in[6];
    const float* w_fc  = (const float*)d_in[7];
    const float* gamma = (const float*)d_in[8];
    const float* beta  = (const float*)d_in[9];

    float* out  = (float*)d_out;
    float* attn = out + (size_t)4 * 1024 * 1024; // second tuple output

    char* ws = (char*)d_ws;
    bf16* wqT   = (bf16*)(ws + (0ull  << 20));
    bf16* wkT   = (bf16*)(ws + (2ull  << 20));
    bf16* wvT   = (bf16*)(ws + (4ull  << 20));
    bf16* wfcT  = (bf16*)(ws + (6ull  << 20));
    bf16* Qh    = (bf16*)(ws + (8ull  << 20));
    bf16* Kh    = (bf16*)(ws + (16ull << 20));
    bf16* Vh    = (bf16*)(ws + (24ull << 20));
    bf16* VhT   = (bf16*)(ws + (32ull << 20));
    bf16* ctx   = (bf16*)(ws + (40ull << 20));
    float* preLN = (float*)(ws + (48ull << 20));

    wt_cvt<<<dim3(32, 32, 4), dim3(32, 8), 0, stream>>>(w_qs, w_ks, w_vs, w_fc,
                                                        wqT, wkT, wvT, wfcT);
    proj_gemm<<<dim3(8, 32, 3), 256, 0, stream>>>(q, k, v, wqT, wkT, wvT, Qh, Kh, Vh);
    vh_t<<<dim3(16, 64), dim3(64, 8), 0, stream>>>(Vh, VhT);
    attn_pv<<<dim3(64, 64), 512, 0, stream>>>(Qh, Kh, VhT, mask, attn, ctx);
    fc_gemm<<<dim3(8, 32), 256, 0, stream>>>(ctx, wfcT, q, preLN);
    ln_kernel<<<4096, 256, 0, stream>>>(preLN, gamma, beta, out);
}